// Round 4
// baseline (173.128 us; speedup 1.0000x reference)
//
#include <hip/hip_runtime.h>

// DiffusionPropagate: out[b,i] = 1 - prod_j (1 - adj[j,i] * p[b,j]), 3 iterations.
// B=4, N=4096. Memory-bound: adj (64 MiB) streamed once per iteration for all
// 4 batches. j-reduction split into CHUNKS partial products (no float atomic
// multiply), combined by a tiny stage-2 kernel. CHUNKS chosen at runtime from
// ws_size (constant across calls -> graph-capture safe).

#define N 4096
#define B 4
#define T1 128              // threads per stage1 block (2 waves)
#define ITILE (T1 * 4)      // 512 output nodes per block (float4 per thread)

template <int CHUNKS>
__global__ __launch_bounds__(T1) void diffusion_stage1(
    const float* __restrict__ adj,     // [N][N] row-major
    const float* __restrict__ p,       // [B][N]
    float* __restrict__ partial) {     // [CHUNKS][B][N]
    constexpr int JC = N / CHUNKS;
    // Transposed p-chunk: lds_p[j][b] = p[b][j0+j]; 16B-aligned so one
    // ds_read_b128 per j broadcasts all 4 batch values (conflict-free).
    __shared__ __align__(16) float lds_p[JC][B];

    const int tid = threadIdx.x;
    const int i0  = blockIdx.x * ITILE + tid * 4;  // first of 4 output nodes
    const int j0  = blockIdx.y * JC;               // chunk start in source dim

    for (int t = tid; t < JC * B; t += T1) {
        int j = t >> 2, b = t & 3;
        lds_p[j][b] = p[b * N + j0 + j];
    }
    __syncthreads();

    float4 acc[B];
#pragma unroll
    for (int b = 0; b < B; ++b) acc[b] = make_float4(1.f, 1.f, 1.f, 1.f);

    const float* aptr = adj + (size_t)j0 * N + i0;

#pragma unroll 4
    for (int j = 0; j < JC; ++j) {
        float4 a  = *reinterpret_cast<const float4*>(aptr + (size_t)j * N);
        float4 pv = *reinterpret_cast<const float4*>(&lds_p[j][0]);
        const float pb[4] = {pv.x, pv.y, pv.z, pv.w};
#pragma unroll
        for (int b = 0; b < B; ++b) {
            acc[b].x *= fmaf(-a.x, pb[b], 1.f);
            acc[b].y *= fmaf(-a.y, pb[b], 1.f);
            acc[b].z *= fmaf(-a.z, pb[b], 1.f);
            acc[b].w *= fmaf(-a.w, pb[b], 1.f);
        }
    }

    const int c = blockIdx.y;
#pragma unroll
    for (int b = 0; b < B; ++b) {
        *reinterpret_cast<float4*>(partial + ((size_t)(c * B + b)) * N + i0) = acc[b];
    }
}

template <int CHUNKS>
__global__ __launch_bounds__(256) void diffusion_stage2(
    const float* __restrict__ partial,  // [CHUNKS][B][N]
    float* __restrict__ pout) {         // [B][N]
    int t = blockIdx.x * 256 + threadIdx.x;  // 0 .. B*N-1
    int b = t >> 12;        // /N
    int i = t & (N - 1);    // %N
    float prod = 1.f;
#pragma unroll
    for (int c = 0; c < CHUNKS; ++c)
        prod *= partial[((size_t)(c * B + b)) * N + i];
    pout[t] = 1.f - prod;
}

// No-workspace fallback: each thread fully reduces one output column for all
// 4 batches. Slow (16 blocks) but needs no partial buffer.
__global__ __launch_bounds__(256) void diffusion_full(
    const float* __restrict__ adj, const float* __restrict__ p,
    float* __restrict__ pout) {
    int i = blockIdx.x * 256 + threadIdx.x;  // 0..N-1
    float acc[B] = {1.f, 1.f, 1.f, 1.f};
    for (int j = 0; j < N; ++j) {
        float a = adj[(size_t)j * N + i];
#pragma unroll
        for (int b = 0; b < B; ++b) acc[b] *= fmaf(-a, p[b * N + j], 1.f);
    }
#pragma unroll
    for (int b = 0; b < B; ++b) pout[b * N + i] = 1.f - acc[b];
}

template <int CHUNKS>
static void run_iters(const float* adj, const float* preds, float* out,
                      float* p0, float* partial, hipStream_t stream) {
    dim3 g1(N / ITILE, CHUNKS), b1(T1);
    dim3 g2((B * N) / 256), b2(256);
    // iter 1: preds -> out ; iter 2: out -> p0 ; iter 3: p0 -> out
    diffusion_stage1<CHUNKS><<<g1, b1, 0, stream>>>(adj, preds, partial);
    diffusion_stage2<CHUNKS><<<g2, b2, 0, stream>>>(partial, out);
    diffusion_stage1<CHUNKS><<<g1, b1, 0, stream>>>(adj, out, partial);
    diffusion_stage2<CHUNKS><<<g2, b2, 0, stream>>>(partial, p0);
    diffusion_stage1<CHUNKS><<<g1, b1, 0, stream>>>(adj, p0, partial);
    diffusion_stage2<CHUNKS><<<g2, b2, 0, stream>>>(partial, out);
}

extern "C" void kernel_launch(void* const* d_in, const int* in_sizes, int n_in,
                              void* d_out, int out_size, void* d_ws, size_t ws_size,
                              hipStream_t stream) {
    const float* preds = (const float*)d_in[0];  // [B][N]
    const float* adj   = (const float*)d_in[1];  // [N][N]
    // d_in[2] = niter (always 3; graph capture requires identical work anyway)
    float* out = (float*)d_out;

    float* p0      = (float*)d_ws;               // B*N floats (ping-pong scratch)
    float* partial = p0 + (size_t)B * N;         // CHUNKS*B*N floats

    const size_t pbytes  = (size_t)B * N * sizeof(float);          // 64 KiB
    const size_t need64  = pbytes + 64 * (size_t)B * N * sizeof(float);  // ~4.06 MiB
    const size_t need4   = pbytes + 4  * (size_t)B * N * sizeof(float);  // 320 KiB

    if (ws_size >= need64) {
        run_iters<64>(adj, preds, out, p0, partial, stream);   // fast path: 512 blocks
    } else if (ws_size >= need4) {
        run_iters<4>(adj, preds, out, p0, partial, stream);    // 32 blocks
    } else {
        // minimal-scratch fallback (needs 64 KiB for p0)
        dim3 g(N / 256), b(256);
        diffusion_full<<<g, b, 0, stream>>>(adj, preds, out);
        diffusion_full<<<g, b, 0, stream>>>(adj, out, p0);
        diffusion_full<<<g, b, 0, stream>>>(adj, p0, out);
    }
}

// Round 5
// 160.015 us; speedup vs baseline: 1.0819x; 1.0819x over previous
//
#include <hip/hip_runtime.h>

// DiffusionPropagate: out[b,i] = 1 - prod_j (1 - adj[j,i] * p[b,j]), 3 iterations.
// B=4, N=4096. Memory-bound: adj (64 MiB) streamed once per iteration for all
// 4 batches. j-reduction split into CHUNKS partial products, combined by a
// small stage-2 kernel. R4 post-mortem: 1 wave/SIMD + unroll-4 was
// latency-bound (~1.4 TB/s). R5: CHUNKS=128 -> 1024 blocks (2 waves/SIMD) and
// unroll 8 (8 KiB in flight/wave). ws_size confirmed 256 MiB by R4 profile.

#define N 4096
#define B 4
#define CHUNKS 128
#define JC (N / CHUNKS)     // 32 j per chunk
#define T1 128              // threads per stage1 block (2 waves)
#define ITILE (T1 * 4)      // 512 output nodes per block (float4 per thread)

__global__ __launch_bounds__(T1) void diffusion_stage1(
    const float* __restrict__ adj,     // [N][N] row-major
    const float* __restrict__ p,       // [B][N]
    float* __restrict__ partial) {     // [CHUNKS][B][N]
    // Transposed p-chunk: lds_p[j][b] = p[b][j0+j]; one ds_read_b128 per j
    // broadcasts all 4 batch values (same address across lanes -> conflict-free).
    __shared__ __align__(16) float lds_p[JC][B];

    const int tid = threadIdx.x;
    const int i0  = blockIdx.x * ITILE + tid * 4;  // first of 4 output nodes
    const int j0  = blockIdx.y * JC;               // chunk start in source dim

    if (tid < JC * B) {  // 128 threads load 128 floats
        int j = tid >> 2, b = tid & 3;
        lds_p[j][b] = p[b * N + j0 + j];
    }
    __syncthreads();

    float4 acc[B];
#pragma unroll
    for (int b = 0; b < B; ++b) acc[b] = make_float4(1.f, 1.f, 1.f, 1.f);

    const float* aptr = adj + (size_t)j0 * N + i0;

#pragma unroll 8
    for (int j = 0; j < JC; ++j) {
        float4 a  = *reinterpret_cast<const float4*>(aptr + (size_t)j * N);
        float4 pv = *reinterpret_cast<const float4*>(&lds_p[j][0]);
        const float pb[4] = {pv.x, pv.y, pv.z, pv.w};
#pragma unroll
        for (int b = 0; b < B; ++b) {
            acc[b].x *= fmaf(-a.x, pb[b], 1.f);
            acc[b].y *= fmaf(-a.y, pb[b], 1.f);
            acc[b].z *= fmaf(-a.z, pb[b], 1.f);
            acc[b].w *= fmaf(-a.w, pb[b], 1.f);
        }
    }

    const int c = blockIdx.y;
#pragma unroll
    for (int b = 0; b < B; ++b) {
        *reinterpret_cast<float4*>(partial + ((size_t)(c * B + b)) * N + i0) = acc[b];
    }
}

__global__ __launch_bounds__(256) void diffusion_stage2(
    const float* __restrict__ partial,  // [CHUNKS][B][N]
    float* __restrict__ pout) {         // [B][N]
    int t = blockIdx.x * 256 + threadIdx.x;  // 0 .. B*N-1
    int b = t >> 12;        // /N
    int i = t & (N - 1);    // %N
    float prod = 1.f;
    // unroll 16 -> ~16 outstanding dword loads per lane (4 KiB/wave in flight)
#pragma unroll 16
    for (int c = 0; c < CHUNKS; ++c)
        prod *= partial[((size_t)(c * B + b)) * N + i];
    pout[t] = 1.f - prod;
}

// Minimal-scratch fallback (kept for safety; R4 confirmed ws = 256 MiB so the
// fast path runs in practice).
__global__ __launch_bounds__(256) void diffusion_full(
    const float* __restrict__ adj, const float* __restrict__ p,
    float* __restrict__ pout) {
    int i = blockIdx.x * 256 + threadIdx.x;  // 0..N-1
    float acc[B] = {1.f, 1.f, 1.f, 1.f};
    for (int j = 0; j < N; ++j) {
        float a = adj[(size_t)j * N + i];
#pragma unroll
        for (int b = 0; b < B; ++b) acc[b] *= fmaf(-a, p[b * N + j], 1.f);
    }
#pragma unroll
    for (int b = 0; b < B; ++b) pout[b * N + i] = 1.f - acc[b];
}

extern "C" void kernel_launch(void* const* d_in, const int* in_sizes, int n_in,
                              void* d_out, int out_size, void* d_ws, size_t ws_size,
                              hipStream_t stream) {
    const float* preds = (const float*)d_in[0];  // [B][N]
    const float* adj   = (const float*)d_in[1];  // [N][N]
    // d_in[2] = niter (always 3; graph capture requires identical work anyway)
    float* out = (float*)d_out;

    float* p0      = (float*)d_ws;               // B*N floats (ping-pong scratch)
    float* partial = p0 + (size_t)B * N;         // CHUNKS*B*N floats (8 MiB)

    const size_t need = ((size_t)B * N + (size_t)CHUNKS * B * N) * sizeof(float);

    if (ws_size >= need) {
        dim3 g1(N / ITILE, CHUNKS), b1(T1);      // 8 x 128 = 1024 blocks
        dim3 g2((B * N) / 256), b2(256);         // 64 blocks
        // iter 1: preds -> out ; iter 2: out -> p0 ; iter 3: p0 -> out
        diffusion_stage1<<<g1, b1, 0, stream>>>(adj, preds, partial);
        diffusion_stage2<<<g2, b2, 0, stream>>>(partial, out);
        diffusion_stage1<<<g1, b1, 0, stream>>>(adj, out, partial);
        diffusion_stage2<<<g2, b2, 0, stream>>>(partial, p0);
        diffusion_stage1<<<g1, b1, 0, stream>>>(adj, p0, partial);
        diffusion_stage2<<<g2, b2, 0, stream>>>(partial, out);
    } else {
        dim3 g(N / 256), b(256);
        diffusion_full<<<g, b, 0, stream>>>(adj, preds, out);
        diffusion_full<<<g, b, 0, stream>>>(adj, out, p0);
        diffusion_full<<<g, b, 0, stream>>>(adj, p0, out);
    }
}